// Round 2
// baseline (174.977 us; speedup 1.0000x reference)
//
#include <hip/hip_runtime.h>

// QueryAndGroup: ball_query(new_xyz, xyz, r=0.2, ns=32) + group xyz (centered) and
// features, concat to out[B][3+C][M][NS].
//
// Shapes (fixed by setup_inputs):
//   xyz      [8][16384][3] f32   d_in[0]
//   new_xyz  [8][1024][3]  f32   d_in[1]
//   features [8][64][16384] f32  d_in[2]
//   out      [8][67][1024][32] f32
//
// Strategy: 1 wave per query point (8192 queries, 4 waves/block -> 2048 blocks).
// Phase 1: ordered scan of the 16384 candidates in chunks of 64; ballot +
// prefix-popcount writes hits in index order until 32 found (matches
// jnp.sort-of-masked-indices semantics exactly). Early exit when full.
// Phase 2: same wave gathers 67*32 output values for its query.
//
// Distance math uses __fsub_rn/__fmul_rn/__fadd_rn in ((dx2+dy2)+dz2) order to
// bit-match the numpy reference (no FMA contraction) -> identical index sets.

#define N_PTS   16384
#define M_Q     1024
#define B_SZ    8
#define NSAMP   32
#define NCH     64
#define R2      0.04f
#define OUT_CH  (3 + NCH)

__global__ __launch_bounds__(256) void qg_kernel(
    const float* __restrict__ xyz,      // [B][N][3]
    const float* __restrict__ new_xyz,  // [B][M][3]
    const float* __restrict__ feat,     // [B][C][N]
    float* __restrict__ out)            // [B][3+C][M][NS]
{
    const int tid  = threadIdx.x;
    const int w    = tid >> 6;          // wave id within block (0..3)
    const int lane = tid & 63;
    const int q    = blockIdx.x * 4 + w;   // global query id
    const int b    = q >> 10;              // q / 1024
    const int m    = q & (M_Q - 1);

    __shared__ int idx_sh[4][NSAMP];
    __shared__ int cnt_sh[4];

    // query center (uniform across the wave)
    const float cx = new_xyz[q * 3 + 0];
    const float cy = new_xyz[q * 3 + 1];
    const float cz = new_xyz[q * 3 + 2];

    const float* __restrict__ xb = xyz + (size_t)b * N_PTS * 3;

    // ---- Phase 1: ordered ball query ----
    int cnt = 0;  // uniform across wave (derived from ballot)
    for (int base = 0; base < N_PTS && cnt < NSAMP; base += 64) {
        const int n = base + lane;
        const float px = xb[n * 3 + 0];
        const float py = xb[n * 3 + 1];
        const float pz = xb[n * 3 + 2];
        const float dx = __fsub_rn(cx, px);
        const float dy = __fsub_rn(cy, py);
        const float dz = __fsub_rn(cz, pz);
        const float d2 = __fadd_rn(__fadd_rn(__fmul_rn(dx, dx), __fmul_rn(dy, dy)),
                                   __fmul_rn(dz, dz));
        const bool hit = d2 < R2;
        const unsigned long long mask = __ballot(hit);
        const int rank = __popcll(mask & ((1ull << lane) - 1ull));
        if (hit) {
            const int slot = cnt + rank;
            if (slot < NSAMP) idx_sh[w][slot] = n;
        }
        cnt += (int)__popcll(mask);
    }
    if (lane == 0) cnt_sh[w] = cnt;
    __syncthreads();

    // fill empty slots with first index (reference: broadcast sorted_idx[...,0])
    {
        const int total = cnt_sh[w];
        if (lane < NSAMP) {
            int v0 = (total > 0) ? idx_sh[w][0] : 0;  // total==0 ~impossible for this data
            if (lane >= total) idx_sh[w][lane] = v0;
        }
    }
    __syncthreads();

    // ---- Phase 2: gather + write ----
    const float* __restrict__ fb = feat + (size_t)b * NCH * N_PTS;
    float* __restrict__ ob = out + ((size_t)b * OUT_CH * M_Q + (size_t)m) * NSAMP;

    // e = c*32 + s, e in [0, 67*32)
    for (int e = lane; e < OUT_CH * NSAMP; e += 64) {
        const int c = e >> 5;
        const int s = e & 31;
        const int n = idx_sh[w][s];
        float v;
        if (c < 3) {
            const float ctr = (c == 0) ? cx : ((c == 1) ? cy : cz);
            v = __fsub_rn(xb[n * 3 + c], ctr);
        } else {
            v = fb[(size_t)(c - 3) * N_PTS + n];
        }
        ob[(size_t)c * (M_Q * NSAMP) + s] = v;
    }
}

extern "C" void kernel_launch(void* const* d_in, const int* in_sizes, int n_in,
                              void* d_out, int out_size, void* d_ws, size_t ws_size,
                              hipStream_t stream) {
    const float* xyz     = (const float*)d_in[0];
    const float* new_xyz = (const float*)d_in[1];
    const float* feat    = (const float*)d_in[2];
    float* out           = (float*)d_out;

    const int n_query = B_SZ * M_Q;              // 8192
    const int blocks  = n_query / 4;             // 4 waves (queries) per 256-thr block
    qg_kernel<<<blocks, 256, 0, stream>>>(xyz, new_xyz, feat, out);
}

// Round 3
// 140.840 us; speedup vs baseline: 1.2424x; 1.2424x over previous
//
#include <hip/hip_runtime.h>

// QueryAndGroup: ball_query(r=0.2, ns=32) + group xyz (centered) + group features.
//   xyz      [8][16384][3] f32   d_in[0]
//   new_xyz  [8][1024][3]  f32   d_in[1]
//   features [8][64][16384] f32  d_in[2]
//   out      [8][67][1024][32] f32
//
// R2 evidence: baseline 100 us at 1.1 TB/s, VALUBusy 8% -> gather-transaction
// bound (17.8M scattered 4B loads, 6% line utilization). Fix: pre-transpose
// features to [N][C] in d_ws so each sample's 64 channels are one 256B row;
// gather via float4 (128B segments), LDS-transpose to [c][s], coalesced stores.

#define N_PTS   16384
#define M_Q     1024
#define B_SZ    8
#define NSAMP   32
#define NCH     64
#define R2      0.04f
#define OUT_CH  (3 + NCH)

// ---------- features [B][C][N] -> ft [B][N][C] ----------
__global__ __launch_bounds__(256) void transpose_kernel(
    const float* __restrict__ feat, float* __restrict__ ft)
{
    __shared__ float tile[64][65];                 // +1 pad: conflict-free
    const int b   = blockIdx.x >> 8;               // 256 n-tiles per batch
    const int n0  = (blockIdx.x & 255) << 6;
    const int tid = threadIdx.x;
    const float* __restrict__ fb = feat + (size_t)b * NCH * N_PTS;
    float* __restrict__ tb       = ft   + ((size_t)b * N_PTS + n0) * NCH;

#pragma unroll
    for (int j = 0; j < 16; ++j) {                 // read coalesced along n
        const int idx = j * 256 + tid;
        const int c = idx >> 6, nn = idx & 63;
        tile[c][nn] = fb[(size_t)c * N_PTS + n0 + nn];
    }
    __syncthreads();
#pragma unroll
    for (int j = 0; j < 16; ++j) {                 // write coalesced along c
        const int idx = j * 256 + tid;
        const int nn = idx >> 6, cc = idx & 63;
        tb[(size_t)nn * NCH + cc] = tile[cc][nn];
    }
}

// ---------- main: ball query + grouped gather from ft [B][N][C] ----------
__global__ __launch_bounds__(128) void qg_main(
    const float* __restrict__ xyz,      // [B][N][3]
    const float* __restrict__ new_xyz,  // [B][M][3]
    const float* __restrict__ ft,       // [B][N][C]
    float* __restrict__ out)            // [B][67][M][NS]
{
    const int tid  = threadIdx.x;
    const int w    = tid >> 6;                 // wave in block (0..1)
    const int lane = tid & 63;
    const int q    = blockIdx.x * 2 + w;
    const int b    = q >> 10;
    const int m    = q & (M_Q - 1);

    __shared__ int   idx_sh[2][NSAMP];
    __shared__ float tile[2][32][33];          // [wave][c_local][s], pad 33: conflict-free

    const float cx = new_xyz[q * 3 + 0];
    const float cy = new_xyz[q * 3 + 1];
    const float cz = new_xyz[q * 3 + 2];
    const float* __restrict__ xb = xyz + (size_t)b * N_PTS * 3;

    // ---- Phase 1: ordered ball query, 2x64 unrolled to halve dependent chain ----
    const unsigned long long lmask = (1ull << lane) - 1ull;
    int cnt = 0;
    for (int base = 0; base < N_PTS && cnt < NSAMP; base += 128) {
        const int nA = base + lane;
        const int nB = base + 64 + lane;
        const float ax = xb[nA * 3 + 0], ay = xb[nA * 3 + 1], az = xb[nA * 3 + 2];
        const float bx = xb[nB * 3 + 0], by = xb[nB * 3 + 1], bz = xb[nB * 3 + 2];

        {   // chunk A (ordered before B)
            const float dx = __fsub_rn(cx, ax), dy = __fsub_rn(cy, ay), dz = __fsub_rn(cz, az);
            const float d2 = __fadd_rn(__fadd_rn(__fmul_rn(dx, dx), __fmul_rn(dy, dy)),
                                       __fmul_rn(dz, dz));
            const bool hit = d2 < R2;
            const unsigned long long mk = __ballot(hit);
            if (hit) {
                const int slot = cnt + __popcll(mk & lmask);
                if (slot < NSAMP) idx_sh[w][slot] = nA;
            }
            cnt += (int)__popcll(mk);
        }
        {   // chunk B
            const float dx = __fsub_rn(cx, bx), dy = __fsub_rn(cy, by), dz = __fsub_rn(cz, bz);
            const float d2 = __fadd_rn(__fadd_rn(__fmul_rn(dx, dx), __fmul_rn(dy, dy)),
                                       __fmul_rn(dz, dz));
            const bool hit = d2 < R2;
            const unsigned long long mk = __ballot(hit);
            if (hit) {
                const int slot = cnt + __popcll(mk & lmask);
                if (slot < NSAMP) idx_sh[w][slot] = nB;
            }
            cnt += (int)__popcll(mk);
        }
    }
    __syncthreads();

    // fill empty slots with first hit (reference broadcasts sorted_idx[...,0])
    if (lane < NSAMP) {
        const int v0 = (cnt > 0) ? idx_sh[w][0] : 0;
        if (lane >= cnt) idx_sh[w][lane] = v0;
    }
    __syncthreads();

    // ---- Phase 2a: centered xyz channels (96 elems, tiny L2-resident gathers) ----
    float* __restrict__ ob = out + ((size_t)b * OUT_CH * M_Q + (size_t)m) * NSAMP;
    for (int e = lane; e < 3 * NSAMP; e += 64) {
        const int c = e >> 5, s = e & 31;
        const int n = idx_sh[w][s];
        const float ctr = (c == 0) ? cx : ((c == 1) ? cy : cz);
        ob[(size_t)c * (M_Q * NSAMP) + s] = __fsub_rn(xb[n * 3 + c], ctr);
    }

    // ---- Phase 2b: features via ft rows (256B contiguous per sample) ----
    const float* __restrict__ ftb = ft + (size_t)b * N_PTS * NCH;
    const int sgrp = lane >> 3;          // 0..7  : sample sub-offset
    const int c4   = lane & 7;           // float4 slot within 32-ch half-row

    for (int chunk = 0; chunk < 2; ++chunk) {
        float4 vals[4];
#pragma unroll
        for (int i = 0; i < 4; ++i) {    // 8 lanes x 128B = full-line segments
            const int s = i * 8 + sgrp;
            const int n = idx_sh[w][s];
            const float4* row = (const float4*)(ftb + (size_t)n * NCH + chunk * 32);
            vals[i] = row[c4];
        }
        __syncthreads();                 // protect tile reuse across chunks
#pragma unroll
        for (int i = 0; i < 4; ++i) {    // LDS transpose: [s][c] -> [c][s]
            const int s = i * 8 + sgrp;
            tile[w][c4 * 4 + 0][s] = vals[i].x;
            tile[w][c4 * 4 + 1][s] = vals[i].y;
            tile[w][c4 * 4 + 2][s] = vals[i].z;
            tile[w][c4 * 4 + 3][s] = vals[i].w;
        }
        __syncthreads();
#pragma unroll
        for (int j = 0; j < 16; ++j) {   // coalesced stores: 2x128B per instr
            const int idx = j * 64 + lane;
            const int c_local = idx >> 5;
            const int s = idx & 31;
            ob[(size_t)(3 + chunk * 32 + c_local) * (M_Q * NSAMP) + s] =
                tile[w][c_local][s];
        }
    }
}

// ---------- fallback (ws too small): round-0 direct-gather kernel ----------
__global__ __launch_bounds__(256) void qg_fallback(
    const float* __restrict__ xyz, const float* __restrict__ new_xyz,
    const float* __restrict__ feat, float* __restrict__ out)
{
    const int tid  = threadIdx.x;
    const int w    = tid >> 6;
    const int lane = tid & 63;
    const int q    = blockIdx.x * 4 + w;
    const int b    = q >> 10;
    const int m    = q & (M_Q - 1);

    __shared__ int idx_sh[4][NSAMP];

    const float cx = new_xyz[q * 3 + 0];
    const float cy = new_xyz[q * 3 + 1];
    const float cz = new_xyz[q * 3 + 2];
    const float* __restrict__ xb = xyz + (size_t)b * N_PTS * 3;

    int cnt = 0;
    for (int base = 0; base < N_PTS && cnt < NSAMP; base += 64) {
        const int n = base + lane;
        const float dx = __fsub_rn(cx, xb[n * 3 + 0]);
        const float dy = __fsub_rn(cy, xb[n * 3 + 1]);
        const float dz = __fsub_rn(cz, xb[n * 3 + 2]);
        const float d2 = __fadd_rn(__fadd_rn(__fmul_rn(dx, dx), __fmul_rn(dy, dy)),
                                   __fmul_rn(dz, dz));
        const bool hit = d2 < R2;
        const unsigned long long mk = __ballot(hit);
        if (hit) {
            const int slot = cnt + __popcll(mk & ((1ull << lane) - 1ull));
            if (slot < NSAMP) idx_sh[w][slot] = n;
        }
        cnt += (int)__popcll(mk);
    }
    __syncthreads();
    if (lane < NSAMP) {
        const int v0 = (cnt > 0) ? idx_sh[w][0] : 0;
        if (lane >= cnt) idx_sh[w][lane] = v0;
    }
    __syncthreads();

    const float* __restrict__ fb = feat + (size_t)b * NCH * N_PTS;
    float* __restrict__ ob = out + ((size_t)b * OUT_CH * M_Q + (size_t)m) * NSAMP;
    for (int e = lane; e < OUT_CH * NSAMP; e += 64) {
        const int c = e >> 5, s = e & 31;
        const int n = idx_sh[w][s];
        float v;
        if (c < 3) {
            const float ctr = (c == 0) ? cx : ((c == 1) ? cy : cz);
            v = __fsub_rn(xb[n * 3 + c], ctr);
        } else {
            v = fb[(size_t)(c - 3) * N_PTS + n];
        }
        ob[(size_t)c * (M_Q * NSAMP) + s] = v;
    }
}

extern "C" void kernel_launch(void* const* d_in, const int* in_sizes, int n_in,
                              void* d_out, int out_size, void* d_ws, size_t ws_size,
                              hipStream_t stream) {
    const float* xyz     = (const float*)d_in[0];
    const float* new_xyz = (const float*)d_in[1];
    const float* feat    = (const float*)d_in[2];
    float* out           = (float*)d_out;

    const size_t need = (size_t)B_SZ * N_PTS * NCH * sizeof(float);  // 33.6 MB
    if (ws_size >= need) {
        transpose_kernel<<<B_SZ * (N_PTS / 64), 256, 0, stream>>>(feat, (float*)d_ws);
        qg_main<<<(B_SZ * M_Q) / 2, 128, 0, stream>>>(xyz, new_xyz, (const float*)d_ws, out);
    } else {
        qg_fallback<<<(B_SZ * M_Q) / 4, 256, 0, stream>>>(xyz, new_xyz, feat, out);
    }
}